// Round 2
// baseline (253.693 us; speedup 1.0000x reference)
//
#include <hip/hip_runtime.h>
#include <hip/hip_bf16.h>
#include <cstdint>
#include <cstddef>

// LSTMCell: gates = [input|hx] @ [Wih|Whh]^T + b_ih + b_hh  (4096 x 4096 x K=2048)
// Split-bf16 (hi+lo) 3-product MFMA GEMM (fp32-class accuracy), fused LSTM epilogue.
// Round 2: 256x256 tile, 8-wave, 4-phase schedule with counted vmcnt(8) (T3+T4) + setprio (T5).

#define B_ROWS 4096
#define HDIM   1024
#define KDIM   2048
#define BM     256
#define BN     256
#define BK     32
#define T_STEPS (KDIM / BK)   // 64

typedef unsigned short u16;
using f32x4  = __attribute__((ext_vector_type(4))) float;
using short8 = __attribute__((ext_vector_type(8))) short;

__device__ __forceinline__ u16 f2bf(float f) {
    unsigned int u = __builtin_bit_cast(unsigned int, f);
    u += 0x7FFFu + ((u >> 16) & 1u);
    return (u16)(u >> 16);
}
__device__ __forceinline__ float bf2f(u16 s) {
    unsigned int u = ((unsigned int)s) << 16;
    return __builtin_bit_cast(float, u);
}

// ---------------- pack: f32 -> bf16 hi/lo, concat K-dim ----------------
__global__ void pack_kernel(const float* __restrict__ input, const float* __restrict__ hx,
                            const float* __restrict__ wih, const float* __restrict__ whh,
                            u16* __restrict__ Ah, u16* __restrict__ Al,
                            u16* __restrict__ Wh, u16* __restrict__ Wl)
{
    const int PER = (B_ROWS * KDIM) / 4;
    int stride = gridDim.x * blockDim.x;
    for (int i = blockIdx.x * blockDim.x + threadIdx.x; i < 2 * PER; i += stride) {
        int isW = (i >= PER) ? 1 : 0;
        int e = i - isW * PER;
        int row = e >> 9;
        int k = (e & 511) << 2;
        const float* s0 = isW ? wih : input;
        const float* s1 = isW ? whh : hx;
        const float* src = (k < 1024) ? (s0 + (size_t)row * 1024 + k)
                                      : (s1 + (size_t)row * 1024 + (k - 1024));
        float4 v = *(const float4*)src;
        u16 h0 = f2bf(v.x), h1 = f2bf(v.y), h2 = f2bf(v.z), h3 = f2bf(v.w);
        u16 l0 = f2bf(v.x - bf2f(h0));
        u16 l1 = f2bf(v.y - bf2f(h1));
        u16 l2 = f2bf(v.z - bf2f(h2));
        u16 l3 = f2bf(v.w - bf2f(h3));
        size_t doff = (size_t)row * KDIM + k;
        u16* dh = (isW ? Wh : Ah) + doff;
        u16* dl = (isW ? Wl : Al) + doff;
        *(ushort4*)dh = make_ushort4(h0, h1, h2, h3);
        *(ushort4*)dl = make_ushort4(l0, l1, l2, l3);
    }
}

// ---------------- fused GEMM + LSTM epilogue ----------------
__device__ __forceinline__ void gload16(const void* g, void* l) {
    __builtin_amdgcn_global_load_lds((const __attribute__((address_space(1))) void*)g,
                                     (__attribute__((address_space(3))) void*)l, 16, 0, 0);
}
__device__ __forceinline__ float sigmf(float x) { return 1.0f / (1.0f + __expf(-x)); }
__device__ __forceinline__ float tanhfast(float x) { return 1.0f - 2.0f / (1.0f + __expf(2.0f * x)); }

__device__ __forceinline__ void barrier_mem() {
    asm volatile("" ::: "memory");
    __builtin_amdgcn_s_barrier();
    asm volatile("" ::: "memory");
}

__launch_bounds__(512, 2)
__global__ void lstm_fused(const u16* __restrict__ Ah, const u16* __restrict__ Al,
                           const u16* __restrict__ Wh, const u16* __restrict__ Wl,
                           const float* __restrict__ cx, const float* __restrict__ eps_c,
                           const float* __restrict__ eps_h,
                           const float* __restrict__ bias_ih, const float* __restrict__ bias_hh,
                           const float* __restrict__ noise_q, const float* __restrict__ noise_e,
                           float* __restrict__ out)
{
    // [buf][kc(4)][row(256)][8] u16 = 16 KB per tile-buf; 4 tiles x 2 bufs = 128 KB
    __shared__ __align__(16) u16 lAh[2][4][256][8];
    __shared__ __align__(16) u16 lAl[2][4][256][8];
    __shared__ __align__(16) u16 lWh[2][4][256][8];
    __shared__ __align__(16) u16 lWl[2][4][256][8];

    int bid = blockIdx.x;
    // XCD swizzle: XCD x gets w in [32x, 32x+32) = 2 W-panels (4 MB, L2-resident) x all A panels
    int w = (bid & 7) * 32 + (bid >> 3);
    int mi = w & 15, hq = w >> 4;
    int bm0 = mi * BM;
    int h0 = hq * 64;

    int tid  = threadIdx.x;
    int lane = tid & 63;
    int wid  = tid >> 6;      // 0..7
    int wm   = wid >> 2;      // M half (128 rows)
    int wn   = wid & 3;       // N quarter (64 cols = 16 h x 4 gates)

    // ---- staging thread mapping: tid -> (kc = tid>>8 (+2 per sweep), row = tid&255) ----
    int rS  = tid & 255;
    int kcS = tid >> 8;
    const u16* Asrc_h = Ah + (size_t)(bm0 + rS) * KDIM + kcS * 8;
    const u16* Asrc_l = Al + (size_t)(bm0 + rS) * KDIM + kcS * 8;
    // LDS W row n -> W global row: gate=(n>>4)&3, h = h0 + (n>>6)*16 + (n&15)
    int wgrow = ((rS >> 4) & 3) * 1024 + h0 + (rS >> 6) * 16 + (rS & 15);
    const u16* Wsrc_h = Wh + (size_t)wgrow * KDIM + kcS * 8;
    const u16* Wsrc_l = Wl + (size_t)wgrow * KDIM + kcS * 8;

#define STG(srcp, arr, b, koff) do { \
        gload16((srcp) + (koff),      &arr[b][kcS][rS][0]);     \
        gload16((srcp) + (koff) + 16, &arr[b][kcS + 2][rS][0]); \
    } while (0)

    // ---- fragment read pointers ----
    int fkc = lane >> 4, fr = lane & 15;
    const u16* pAh = &lAh[0][fkc][wm * 128 + fr][0];
    const u16* pAl = &lAl[0][fkc][wm * 128 + fr][0];
    const u16* pWh = &lWh[0][fkc][wn * 64 + fr][0];
    const u16* pWl = &lWl[0][fkc][wn * 64 + fr][0];
    const int BUFO = 4 * 256 * 8;   // u16 per buffer

    f32x4 acc[8][4];
#pragma unroll
    for (int m = 0; m < 8; ++m)
#pragma unroll
        for (int g = 0; g < 4; ++g)
            acc[m][g] = (f32x4){0.f, 0.f, 0.f, 0.f};

    // ---- prologue: stage steps 0 and 1 ----
    STG(Asrc_h, lAh, 0, 0); STG(Asrc_l, lAl, 0, 0);
    STG(Wsrc_h, lWh, 0, 0); STG(Wsrc_l, lWl, 0, 0);
    STG(Asrc_h, lAh, 1, 32); STG(Asrc_l, lAl, 1, 32);
    STG(Wsrc_h, lWh, 1, 32); STG(Wsrc_l, lWl, 1, 32);
    asm volatile("s_waitcnt vmcnt(8)" ::: "memory");
    barrier_mem();

#define READ_A(mbase) do { \
        ah[0] = *(const short8*)(pAh + bo + (mbase) * 128);       \
        ah[1] = *(const short8*)(pAh + bo + ((mbase) + 1) * 128); \
        al[0] = *(const short8*)(pAl + bo + (mbase) * 128);       \
        al[1] = *(const short8*)(pAl + bo + ((mbase) + 1) * 128); \
    } while (0)

#define PHASE_MFMA(m0_) do { \
        __builtin_amdgcn_s_setprio(1); \
        _Pragma("unroll") \
        for (int g = 0; g < 4; ++g) { \
            _Pragma("unroll") \
            for (int mm = 0; mm < 2; ++mm) { \
                acc[(m0_) + mm][g] = __builtin_amdgcn_mfma_f32_16x16x32_bf16(ah[mm], wh[g], acc[(m0_) + mm][g], 0, 0, 0); \
                acc[(m0_) + mm][g] = __builtin_amdgcn_mfma_f32_16x16x32_bf16(al[mm], wh[g], acc[(m0_) + mm][g], 0, 0, 0); \
                acc[(m0_) + mm][g] = __builtin_amdgcn_mfma_f32_16x16x32_bf16(ah[mm], wl[g], acc[(m0_) + mm][g], 0, 0, 0); \
            } \
        } \
        __builtin_amdgcn_s_setprio(0); \
    } while (0)

#pragma unroll 1
    for (int t = 0; t < T_STEPS; ++t) {
        int cur = t & 1;
        int bo = cur * BUFO;
        int koff2 = (t + 2) * 32;
        bool pre = (t < T_STEPS - 2);
        short8 wh[4], wl[4], ah[2], al[2];

        // ---- P0: all W frags + A m0,m1 ----
#pragma unroll
        for (int g = 0; g < 4; ++g) {
            wh[g] = *(const short8*)(pWh + bo + g * 128);
            wl[g] = *(const short8*)(pWl + bo + g * 128);
        }
        READ_A(0);
        barrier_mem();
        asm volatile("s_waitcnt lgkmcnt(0)" ::: "memory");
        PHASE_MFMA(0);
        barrier_mem();

        // ---- P1: A m2,m3 ; stage Wh(t+2) (Wh[cur] reads all completed in P0) ----
        READ_A(2);
        if (pre) STG(Wsrc_h, lWh, cur, koff2);
        barrier_mem();
        asm volatile("s_waitcnt lgkmcnt(0)" ::: "memory");
        PHASE_MFMA(2);
        barrier_mem();

        // ---- P2: A m4,m5 ; stage Wl(t+2) ----
        READ_A(4);
        if (pre) STG(Wsrc_l, lWl, cur, koff2);
        barrier_mem();
        asm volatile("s_waitcnt lgkmcnt(0)" ::: "memory");
        PHASE_MFMA(4);
        barrier_mem();

        // ---- P3: A m6,m7 (no staging: A[cur] still being read) ----
        READ_A(6);
        barrier_mem();
        asm volatile("s_waitcnt lgkmcnt(0)" ::: "memory");
        PHASE_MFMA(6);
        barrier_mem();

        // ---- end of step: A[cur] fully consumed -> stage A(t+2); counted vmcnt ----
        if (pre) {
            STG(Asrc_h, lAh, cur, koff2);
            STG(Asrc_l, lAl, cur, koff2);
            asm volatile("s_waitcnt vmcnt(8)" ::: "memory");   // t+1's loads retired; t+2's in flight
        } else if (t == T_STEPS - 2) {
            asm volatile("s_waitcnt vmcnt(0)" ::: "memory");   // tail: drain last step's loads
        }
        if (t < T_STEPS - 1) barrier_mem();
    }

    // ---- epilogue: gates for (r,h) are lane-local across n-frags ----
    float sq_e = sqrtf(noise_e[0]);
    float sq_q = sqrtf(noise_q[0]);
    int hcol = h0 + wn * 16 + fr;
    float b_i = bias_ih[hcol]        + bias_hh[hcol];
    float b_f = bias_ih[1024 + hcol] + bias_hh[1024 + hcol];
    float b_c = bias_ih[2048 + hcol] + bias_hh[2048 + hcol];
    float b_o = bias_ih[3072 + hcol] + bias_hh[3072 + hcol];
#pragma unroll
    for (int m = 0; m < 8; ++m) {
        int r0 = bm0 + wm * 128 + m * 16 + fkc * 4;
#pragma unroll
        for (int j = 0; j < 4; ++j) {
            int r = r0 + j;
            size_t off = (size_t)r * HDIM + hcol;
            float gi = acc[m][0][j] + b_i;
            float gf = acc[m][1][j] + b_f;
            float gc = acc[m][2][j] + b_c;
            float go = acc[m][3][j] + b_o;
            float ig = sigmf(gi), fg = sigmf(gf);
            float cg = tanhfast(gc), og = sigmf(go);
            float cyv = fg * cx[off] + ig * cg + sq_e * eps_c[off];
            float hyv = og * tanhfast(cyv) + sq_q * eps_h[off];
            out[off] = hyv;                                 // hy
            out[(size_t)B_ROWS * HDIM + off] = cyv;         // cy
        }
    }
}

extern "C" void kernel_launch(void* const* d_in, const int* in_sizes, int n_in,
                              void* d_out, int out_size, void* d_ws, size_t ws_size,
                              hipStream_t stream)
{
    const float* input = (const float*)d_in[0];
    const float* hx    = (const float*)d_in[1];
    const float* cx    = (const float*)d_in[2];
    const float* nq    = (const float*)d_in[3];
    const float* ne    = (const float*)d_in[4];
    const float* wih   = (const float*)d_in[5];
    const float* whh   = (const float*)d_in[6];
    const float* bih   = (const float*)d_in[7];
    const float* bhh   = (const float*)d_in[8];
    const float* epsc  = (const float*)d_in[9];
    const float* epsh  = (const float*)d_in[10];
    float* out = (float*)d_out;

    u16* Ah = (u16*)d_ws;
    u16* Al = Ah + (size_t)B_ROWS * KDIM;
    u16* Wh = Al + (size_t)B_ROWS * KDIM;
    u16* Wl = Wh + (size_t)B_ROWS * KDIM;   // 64 MB of ws total

    hipLaunchKernelGGL(pack_kernel, dim3(2048), dim3(256), 0, stream,
                       input, hx, wih, whh, Ah, Al, Wh, Wl);
    hipLaunchKernelGGL(lstm_fused, dim3(256), dim3(512), 0, stream,
                       Ah, Al, Wh, Wl, cx, epsc, epsh, bih, bhh, nq, ne, out);
}